// Round 4
// baseline (145.167 us; speedup 1.0000x reference)
//
#include <hip/hip_runtime.h>
#include <math.h>

// Problem constants
#define BB 16384
#define TT 99
#define EE 10
#define RR 10
#define LL 3
#define TILE 33          // 99 = 3*33
#define SROW 333         // states LDS stride (floats/row); odd -> (13*l)%32 hits all banks, 2-way free
#define PROW 101         // probs LDS stride (floats/row); odd -> conflict-free
#define BROW 100         // byte stride for sel/y rows

// tanh(x) = 1 - 2/(exp(2x)+1); exact limits at +-inf.
__device__ __forceinline__ float fast_tanh(float x) {
    float e = __expf(2.0f * x);
    return fmaf(-2.0f, __builtin_amdgcn_rcpf(e + 1.0f), 1.0f);
}

// One ROW PER LANE: h stays entirely in registers -> recurrence chain is pure
// FMA+tanh with 10-way ILP; no memory op on the loop-carried dependency.
// Block = 1 wave (64 rows); 256 blocks = 1 wave/CU. All LDS ops are
// fire-and-forget stores or prefetched reads. Single wave per block -> no
// __syncthreads needed (per-wave DS ordering).
__global__ __launch_bounds__(64, 1)
void rnn_row_kernel(const int* __restrict__ tok_ids,
                    const float* __restrict__ labels,
                    const float* __restrict__ emb,
                    const float* __restrict__ W,
                    const float* __restrict__ U,
                    const float* __restrict__ bvec,
                    const float* __restrict__ Wo,
                    const float* __restrict__ bo,
                    float* __restrict__ states_out,
                    float* __restrict__ probs_out,
                    float* __restrict__ ws)
{
    __shared__ float          s_st [64 * SROW];  // 85.2 KB (doubles as raw-label scratch in preamble)
    __shared__ float          s_pr [64 * PROW];  // 25.9 KB
    __shared__ unsigned char  s_sel[64 * BROW];  //  6.4 KB  token class 0/1/2
    __shared__ unsigned char  s_y  [64 * BROW];  //  6.4 KB  label class 0/1/2

    const int l    = threadIdx.x;
    const int row0 = blockIdx.x * 64;

    // ---- preamble 1: tokens -> class bytes (fully coalesced linear) ----
#pragma unroll 4
    for (int i = 0; i < TT; ++i) {                    // 64*99 ints, linear
        const int q  = l + 64 * i;
        const int r  = q / TT;
        const int tt = q - r * TT;
        s_sel[r * BROW + tt] = (unsigned char)tok_ids[(size_t)row0 * TT + q];
    }
    // ---- preamble 2: raw labels -> s_st scratch (coalesced linear) ----
#pragma unroll 4
    for (int i = 0; i < 297; ++i) {                   // 64*99*3 dwords, linear
        const int q = l + 64 * i;
        s_st[q] = labels[(size_t)row0 * (TT * LL) + q];
    }
    // ---- preamble 3: y prepass (lane reads its own row's triples) ----
#pragma unroll 2
    for (int tt = 0; tt < TT; ++tt) {
        const float* lp = &s_st[(l * TT + tt) * LL];
        const float la1 = lp[1], la2 = lp[2];
        s_y[l * BROW + tt] = la1 > 0.5f ? (unsigned char)1
                            : (la2 > 0.5f ? (unsigned char)2 : (unsigned char)0);
    }

    // ---- uniform weights (compiler mixes SGPR/VGPR; occupancy is 1 wave/SIMD anyway) ----
    float Uv[RR][RR];
#pragma unroll
    for (int i = 0; i < RR; ++i)
#pragma unroll
        for (int j = 0; j < RR; ++j)
            Uv[i][j] = U[i * RR + j];

    float c1[RR], c2[RR];
#pragma unroll
    for (int j = 0; j < RR; ++j) { c1[j] = bvec[j]; c2[j] = bvec[j]; }
#pragma unroll
    for (int i = 0; i < EE; ++i) {
        const float e1 = emb[1 * EE + i];
        const float e2 = emb[2 * EE + i];
#pragma unroll
        for (int j = 0; j < RR; ++j) {
            const float w = W[i * RR + j];
            c1[j] = fmaf(e1, w, c1[j]);
            c2[j] = fmaf(e2, w, c2[j]);
        }
    }

    float Wov[RR][LL];
#pragma unroll
    for (int j = 0; j < RR; ++j)
#pragma unroll
        for (int c = 0; c < LL; ++c)
            Wov[j][c] = Wo[j * LL + c];
    const float bo0 = bo[0], bo1 = bo[1], bo2 = bo[2];

    float h[RR];
#pragma unroll
    for (int j = 0; j < RR; ++j) h[j] = 0.0f;

    float loss_acc = 0.0f;
    int   corr = 0;

    // prefetch step 0 bytes into registers
    int sel = (int)s_sel[l * BROW + 0];
    int yv  = (int)s_y  [l * BROW + 0];

#pragma unroll 1
    for (int k = 0; k < 3; ++k) {
#pragma unroll 1
        for (int tt = 0; tt < TILE; ++tt) {
            const int t    = k * TILE + tt;
            const int selc = sel, yc = yv;
            const int tn   = (t + 1 < TT) ? t + 1 : t;
            sel = (int)s_sel[l * BROW + tn];          // prefetch next step
            yv  = (int)s_y  [l * BROW + tn];

            // a = c[tok] ; a += h @ U   (10 independent FMA streams, all regs)
            float a[RR];
            const bool is1 = (selc == 1);
#pragma unroll
            for (int j = 0; j < RR; ++j) a[j] = is1 ? c1[j] : c2[j];
#pragma unroll
            for (int i = 0; i < RR; ++i) {
                const float hi = h[i];
#pragma unroll
                for (int j = 0; j < RR; ++j)
                    a[j] = fmaf(hi, Uv[i][j], a[j]);
            }
            const bool live = (selc != 0);
#pragma unroll
            for (int j = 0; j < RR; ++j) {
                const float hn = fast_tanh(a[j]);
                h[j] = live ? hn : h[j];              // Keras masking: carry h
            }

            // stage states (fire-and-forget ds writes, conflict-free stride)
            float* sp = &s_st[l * SROW + tt * RR];
#pragma unroll
            for (int j = 0; j < RR; ++j) sp[j] = h[j];

            // dense (10x3) + softmax(3), all in registers
            float l0 = bo0, l1 = bo1, l2 = bo2;
#pragma unroll
            for (int j = 0; j < RR; ++j) {
                l0 = fmaf(h[j], Wov[j][0], l0);
                l1 = fmaf(h[j], Wov[j][1], l1);
                l2 = fmaf(h[j], Wov[j][2], l2);
            }
            const float m  = fmaxf(l0, fmaxf(l1, l2));
            const float e0 = __expf(l0 - m), e1 = __expf(l1 - m), e2 = __expf(l2 - m);
            const float rs = __builtin_amdgcn_rcpf(e0 + e1 + e2);
            const float p0 = e0 * rs, p1 = e1 * rs, p2 = e2 * rs;

            float* pp = &s_pr[l * PROW + tt * LL];
            pp[0] = p0; pp[1] = p1; pp[2] = p2;

            // loss (one-hot labels -> single log) + accuracy
            const float py = (yc == 0) ? p0 : ((yc == 1) ? p1 : p2);
            loss_acc -= __logf(fminf(fmaxf(py, 1e-7f), 1.0f));

            int ap = 0; float pm = p0;
            if (p1 > pm) { ap = 1; pm = p1; }
            if (p2 > pm) { ap = 2; }
            corr += (ap == yc) ? 1 : 0;
        }

        // ---- flush states tile: LDS -> global, coalesced float2 ----
        // 64 rows x 330 floats = 10560 float2 pieces, 165 per lane
        {
            const size_t sb = (size_t)row0 * (TT * RR) + (size_t)k * TILE * RR;
#pragma unroll 4
            for (int i = 0; i < 165; ++i) {
                const int q = l + 64 * i;
                const int r = q / 165;
                const int m2 = q - r * 165;           // float2 index within row
                const float v0 = s_st[r * SROW + 2 * m2];
                const float v1 = s_st[r * SROW + 2 * m2 + 1];
                *reinterpret_cast<float2*>(
                    &states_out[sb + (size_t)r * (TT * RR) + 2 * m2]) = make_float2(v0, v1);
            }
        }
        // ---- flush probs tile: 64 rows x 99 floats, coalesced dwords ----
        {
            const size_t pb = (size_t)row0 * (TT * LL) + (size_t)k * TILE * LL;
#pragma unroll 4
            for (int i = 0; i < 99; ++i) {
                const int q = l + 64 * i;
                const int r = q / 99;
                const int m1 = q - r * 99;
                probs_out[pb + (size_t)r * (TT * LL) + m1] = s_pr[r * PROW + m1];
            }
        }
        // next tile reuses s_st/s_pr: same-wave DS ordering guarantees safety
    }

    // ---- wave reduction -> one partial per block (deterministic) ----
    float ls = loss_acc;
    float cs = (float)corr;
#pragma unroll
    for (int off = 32; off > 0; off >>= 1) {
        ls += __shfl_down(ls, off, 64);
        cs += __shfl_down(cs, off, 64);
    }
    if (l == 0) {
        ws[blockIdx.x]       = ls;
        ws[256 + blockIdx.x] = cs;
    }
}

__global__ __launch_bounds__(256)
void finalize_kernel(const float* __restrict__ ws, float* __restrict__ out_tail)
{
    __shared__ float sl[4], sc[4];
    const int t = threadIdx.x;
    float ls = ws[t];
    float cs = ws[256 + t];
#pragma unroll
    for (int off = 32; off > 0; off >>= 1) {
        ls += __shfl_down(ls, off, 64);
        cs += __shfl_down(cs, off, 64);
    }
    if ((t & 63) == 0) { sl[t >> 6] = ls; sc[t >> 6] = cs; }
    __syncthreads();
    if (t == 0) {
        const float L = sl[0] + sl[1] + sl[2] + sl[3];
        const float C = sc[0] + sc[1] + sc[2] + sc[3];
        const float inv = 1.0f / (float)((size_t)BB * TT);
        out_tail[0] = C * inv;   // accuracy
        out_tail[1] = L * inv;   // loss
    }
}

extern "C" void kernel_launch(void* const* d_in, const int* in_sizes, int n_in,
                              void* d_out, int out_size, void* d_ws, size_t ws_size,
                              hipStream_t stream)
{
    const int*   tok    = (const int*)  d_in[0];
    const float* labels = (const float*)d_in[1];
    // d_in[2] = mask (unused by reference math)
    const float* emb = (const float*)d_in[3];
    const float* W   = (const float*)d_in[4];
    const float* U   = (const float*)d_in[5];
    const float* bv  = (const float*)d_in[6];
    const float* Wo  = (const float*)d_in[7];
    const float* bo  = (const float*)d_in[8];

    float* out    = (float*)d_out;
    float* states = out;                                  // [B,T,10]
    float* probs  = out + (size_t)BB * TT * RR;           // [B,T,3]
    float* tail   = out + (size_t)BB * TT * (RR + LL);    // accuracy, loss
    float* ws     = (float*)d_ws;                         // 512 floats used

    rnn_row_kernel<<<BB / 64, 64, 0, stream>>>(tok, labels, emb, W, U, bv, Wo, bo,
                                               states, probs, ws);
    finalize_kernel<<<1, 256, 0, stream>>>(ws, tail);
}

// Round 6
// 141.959 us; speedup vs baseline: 1.0226x; 1.0226x over previous
//
#include <hip/hip_runtime.h>
#include <math.h>

// Problem constants
#define BB 16384
#define TT 99
#define RR 10
#define LL 3
#define TILE 33          // 99 = 3*33
#define SROW 333         // states LDS stride (floats/row); 333%32=13, gcd(13,32)=1 -> conflict-free
#define PROW 101         // probs LDS stride (floats/row); 101%32=5 -> conflict-free
#define CROW 100         // code byte stride/row; dword stride 25, gcd(25,32)=1 -> conflict-free

// tanh(x) = 1 - 2/(exp(2x)+1); exact limits at +-inf.
__device__ __forceinline__ float fast_tanh(float x) {
    float e = __expf(2.0f * x);
    return fmaf(-2.0f, __builtin_amdgcn_rcpf(e + 1.0f), 1.0f);
}

// One ROW PER LANE. All weights staged through LDS and read back with ds_read
// -> results MUST live in VGPRs (LDS reads cannot target SGPRs), so the
// 99-step loop runs entirely out of registers (fix for round 4's VGPR=132
// weight-reload behavior). launch_bounds(64,1) -> up to 512 VGPRs, no spill.
// Block = 1 wave -> no barriers anywhere (per-wave DS ops are in-order).
// ROUND-6 FIX: weight staging used `if (l < 100)` with a 64-lane block, so
// U[64..99]/W[64..99] were never written (stale LDS garbage -> absmax 1.31).
// Now a strided loop covers all 100 elements.
__global__ __launch_bounds__(64, 1)
void rnn_row_kernel(const int* __restrict__ tok_ids,
                    const float* __restrict__ labels,
                    const float* __restrict__ emb,
                    const float* __restrict__ W,
                    const float* __restrict__ U,
                    const float* __restrict__ bvec,
                    const float* __restrict__ Wo,
                    const float* __restrict__ bo,
                    float* __restrict__ states_out,
                    float* __restrict__ probs_out,
                    float* __restrict__ ws)
{
    __shared__ __align__(16) float         s_st[64 * SROW];   // 85,248 B; preamble: raw labels
    __shared__ __align__(16) float         s_pr[64 * PROW];   // 25,856 B; preamble: raw tokens
    __shared__ __align__(16) unsigned char s_code[64 * CROW]; //  6,400 B  (sel<<2)|y per (row,t)
    __shared__ __align__(16) float         s_w[272];          //  1,088 B  weight staging

    const int l    = threadIdx.x;
    const int row0 = blockIdx.x * 64;

    // ---- preamble A: raw tokens -> s_pr (int4, software-pipelined groups) ----
    {
        const int4* tok4 = reinterpret_cast<const int4*>(tok_ids + (size_t)row0 * TT);
        int4* dst = reinterpret_cast<int4*>(s_pr);
        int4 buf[16];
#pragma unroll 1
        for (int g = 0; g < 2; ++g) {            // 2*16*64 = 2048 >= 1584 pieces
#pragma unroll
            for (int u = 0; u < 16; ++u) {
                const int q = l + 64 * (g * 16 + u);
                if (q < (TT * 64 / 4)) buf[u] = tok4[q];
            }
#pragma unroll
            for (int u = 0; u < 16; ++u) {
                const int q = l + 64 * (g * 16 + u);
                if (q < (TT * 64 / 4)) dst[q] = buf[u];
            }
        }
    }
    // ---- preamble B: raw labels -> s_st (float4 groups) ----
    {
        const float4* lab4 = reinterpret_cast<const float4*>(labels + (size_t)row0 * TT * LL);
        float4* dst = reinterpret_cast<float4*>(s_st);
        float4 buf[16];
#pragma unroll 1
        for (int g = 0; g < 5; ++g) {            // 5*16*64 = 5120 >= 4752 pieces
#pragma unroll
            for (int u = 0; u < 16; ++u) {
                const int q = l + 64 * (g * 16 + u);
                if (q < (TT * LL * 64 / 4)) buf[u] = lab4[q];
            }
#pragma unroll
            for (int u = 0; u < 16; ++u) {
                const int q = l + 64 * (g * 16 + u);
                if (q < (TT * LL * 64 / 4)) dst[q] = buf[u];
            }
        }
    }
    // ---- preamble C: weights -> LDS (one-time; strided so ALL 100 elems land) ----
#pragma unroll
    for (int q = 0; q < 2; ++q) {                 // covers 0..127 >= 100
        const int idx = l + 64 * q;
        if (idx < 100) { s_w[idx] = U[idx]; s_w[100 + idx] = W[idx]; }
    }
    if (l < 10)  { s_w[200 + l] = emb[10 + l];    // emb row 1
                   s_w[210 + l] = emb[20 + l];    // emb row 2
                   s_w[220 + l] = bvec[l]; }
    if (l < 30)  { s_w[230 + l] = Wo[l]; }
    if (l < 3)   { s_w[260 + l] = bo[l]; }

    // ---- preamble D: classify own row -> packed code bytes ----
    {
        const int* s_tok_i = reinterpret_cast<const int*>(s_pr);
#pragma unroll 4
        for (int t = 0; t < TT; ++t) {
            const int   tk  = s_tok_i[l * TT + t];
            const float la1 = s_st[(l * TT + t) * LL + 1];
            const float la2 = s_st[(l * TT + t) * LL + 2];
            const int   y   = (la1 > 0.5f) ? 1 : ((la2 > 0.5f) ? 2 : 0);
            s_code[l * CROW + t] = (unsigned char)((tk << 2) | y);
        }
    }

    // ---- weights: LDS -> VGPR arrays (ds_read results are always VGPRs) ----
    float Uv[RR][RR];
#pragma unroll
    for (int i = 0; i < RR; ++i)
#pragma unroll
        for (int j = 0; j < RR; ++j)
            Uv[i][j] = s_w[i * RR + j];

    float c1[RR], c2[RR];
#pragma unroll
    for (int j = 0; j < RR; ++j) { c1[j] = s_w[220 + j]; c2[j] = s_w[220 + j]; }
#pragma unroll
    for (int i = 0; i < RR; ++i) {
        const float e1 = s_w[200 + i];
        const float e2 = s_w[210 + i];
#pragma unroll
        for (int j = 0; j < RR; ++j) {
            const float w = s_w[100 + i * RR + j];
            c1[j] = fmaf(e1, w, c1[j]);
            c2[j] = fmaf(e2, w, c2[j]);
        }
    }
    float Woc[RR][LL];
#pragma unroll
    for (int j = 0; j < RR; ++j)
#pragma unroll
        for (int c = 0; c < LL; ++c)
            Woc[j][c] = s_w[230 + j * LL + c];
    const float bo0 = s_w[260], bo1 = s_w[261], bo2 = s_w[262];

    // ---- main sequential loop: register-only recurrence ----
    float h[RR];
#pragma unroll
    for (int j = 0; j < RR; ++j) h[j] = 0.0f;
    float loss_acc = 0.0f;
    int   corr = 0;

    int code = (int)s_code[l * CROW];            // prefetch t=0

#pragma unroll 1
    for (int k = 0; k < 3; ++k) {
#pragma unroll 1
        for (int tt = 0; tt < TILE; ++tt) {
            const int t   = k * TILE + tt;
            const int cur = code;
            const int tn  = (t + 1 < TT) ? t + 1 : t;
            code = (int)s_code[l * CROW + tn];   // prefetch next step

            const int  sel  = cur >> 2;
            const int  y    = cur & 3;
            const bool is1  = (sel == 1);
            const bool live = (sel != 0);

            float a[RR];
#pragma unroll
            for (int j = 0; j < RR; ++j) a[j] = is1 ? c1[j] : c2[j];
#pragma unroll
            for (int i = 0; i < RR; ++i) {
                const float hi = h[i];
#pragma unroll
                for (int j = 0; j < RR; ++j)
                    a[j] = fmaf(hi, Uv[i][j], a[j]);
            }
#pragma unroll
            for (int j = 0; j < RR; ++j) {
                const float hn = fast_tanh(a[j]);
                h[j] = live ? hn : h[j];          // Keras masking: carry h
            }

            // stage states (fire-and-forget, conflict-free stride)
            float* sp = &s_st[l * SROW + tt * RR];
#pragma unroll
            for (int j = 0; j < RR; ++j) sp[j] = h[j];

            // logits (10x3); softmax WITHOUT max-subtract (|logit| <~ 3)
            float l0 = bo0, l1 = bo1, l2 = bo2;
#pragma unroll
            for (int j = 0; j < RR; ++j) {
                l0 = fmaf(h[j], Woc[j][0], l0);
                l1 = fmaf(h[j], Woc[j][1], l1);
                l2 = fmaf(h[j], Woc[j][2], l2);
            }
            const float e0 = __expf(l0), e1 = __expf(l1), e2 = __expf(l2);
            const float S  = e0 + e1 + e2;
            const float rs = __builtin_amdgcn_rcpf(S);
            float* pp = &s_pr[l * PROW + tt * LL];
            pp[0] = e0 * rs; pp[1] = e1 * rs; pp[2] = e2 * rs;

            // loss: -log(clip(p_y)) == min(logS - l_y, -log(1e-7))
            const float ly   = (y == 0) ? l0 : ((y == 1) ? l1 : l2);
            const float term = fminf(__logf(S) - ly, 16.11809565f);
            loss_acc += term;

            // accuracy: argmax(probs) == argmax(logits) (monotonic, same ties)
            int ap = 0; float pm = l0;
            if (l1 > pm) { ap = 1; pm = l1; }
            if (l2 > pm) { ap = 2; }
            corr += (ap == y) ? 1 : 0;
        }

        // ---- flush states tile: LDS -> global, coalesced float2 ----
        {
            const size_t sb = (size_t)row0 * (TT * RR) + (size_t)k * TILE * RR;
#pragma unroll 4
            for (int i = 0; i < 165; ++i) {
                const int q  = l + 64 * i;
                const int r  = q / 165;
                const int m2 = q - r * 165;
                const float v0 = s_st[r * SROW + 2 * m2];
                const float v1 = s_st[r * SROW + 2 * m2 + 1];
                *reinterpret_cast<float2*>(
                    &states_out[sb + (size_t)r * (TT * RR) + 2 * m2]) = make_float2(v0, v1);
            }
        }
        // ---- flush probs tile: coalesced dwords ----
        {
            const size_t pb = (size_t)row0 * (TT * LL) + (size_t)k * TILE * LL;
#pragma unroll 4
            for (int i = 0; i < 99; ++i) {
                const int q  = l + 64 * i;
                const int r  = q / 99;
                const int m1 = q - r * 99;
                probs_out[pb + (size_t)r * (TT * LL) + m1] = s_pr[r * PROW + m1];
            }
        }
        // next tile reuses s_st/s_pr: same-wave DS ordering guarantees safety
    }

    // ---- wave reduction -> one partial per block (deterministic) ----
    float ls = loss_acc;
    float cs = (float)corr;
#pragma unroll
    for (int off = 32; off > 0; off >>= 1) {
        ls += __shfl_down(ls, off, 64);
        cs += __shfl_down(cs, off, 64);
    }
    if (l == 0) {
        ws[blockIdx.x]       = ls;
        ws[256 + blockIdx.x] = cs;
    }
}

__global__ __launch_bounds__(256)
void finalize_kernel(const float* __restrict__ ws, float* __restrict__ out_tail)
{
    __shared__ float sl[4], sc[4];
    const int t = threadIdx.x;
    float ls = ws[t];
    float cs = ws[256 + t];
#pragma unroll
    for (int off = 32; off > 0; off >>= 1) {
        ls += __shfl_down(ls, off, 64);
        cs += __shfl_down(cs, off, 64);
    }
    if ((t & 63) == 0) { sl[t >> 6] = ls; sc[t >> 6] = cs; }
    __syncthreads();
    if (t == 0) {
        const float L = sl[0] + sl[1] + sl[2] + sl[3];
        const float C = sc[0] + sc[1] + sc[2] + sc[3];
        const float inv = 1.0f / (float)((size_t)BB * TT);
        out_tail[0] = C * inv;   // accuracy
        out_tail[1] = L * inv;   // loss
    }
}

extern "C" void kernel_launch(void* const* d_in, const int* in_sizes, int n_in,
                              void* d_out, int out_size, void* d_ws, size_t ws_size,
                              hipStream_t stream)
{
    const int*   tok    = (const int*)  d_in[0];
    const float* labels = (const float*)d_in[1];
    // d_in[2] = mask (unused by reference math)
    const float* emb = (const float*)d_in[3];
    const float* W   = (const float*)d_in[4];
    const float* U   = (const float*)d_in[5];
    const float* bv  = (const float*)d_in[6];
    const float* Wo  = (const float*)d_in[7];
    const float* bo  = (const float*)d_in[8];

    float* out    = (float*)d_out;
    float* states = out;                                  // [B,T,10]
    float* probs  = out + (size_t)BB * TT * RR;           // [B,T,3]
    float* tail   = out + (size_t)BB * TT * (RR + LL);    // accuracy, loss
    float* ws     = (float*)d_ws;                         // 512 floats used

    rnn_row_kernel<<<BB / 64, 64, 0, stream>>>(tok, labels, emb, W, U, bv, Wo, bo,
                                               states, probs, ws);
    finalize_kernel<<<1, 256, 0, stream>>>(ws, tail);
}

// Round 7
// 140.634 us; speedup vs baseline: 1.0322x; 1.0094x over previous
//
#include <hip/hip_runtime.h>
#include <math.h>

// Problem constants
#define BB 16384
#define TT 99
#define RR 10
#define LL 3
#define TILE 33          // 99 = 3*33
#define SROW 333         // states LDS stride (floats/row); 333%32=13, gcd(13,32)=1 -> conflict-free
#define PROW 101         // probs LDS stride (floats/row); 101%32=5 -> conflict-free
#define CROW 100         // code byte stride/row; dword stride 25, gcd(25,32)=1 -> conflict-free

// Pin a float into a VGPR and make its definition opaque: the compiler can
// neither rematerialize it (re-issue the ds_read each use) nor prove it
// wave-uniform. This is the fix for R4/R6's VGPR_Count=132 reload behavior.
#define KEEP(x) asm("" : "+v"(x))

// tanh(x) = 1 - 2/(exp(2x)+1); exact limits at +-inf.
__device__ __forceinline__ float fast_tanh(float x) {
    float e = __expf(2.0f * x);
    return fmaf(-2.0f, __builtin_amdgcn_rcpf(e + 1.0f), 1.0f);
}

// One ROW PER LANE: h and ALL weights in VGPRs -> the 99-step recurrence is
// pure FMA/tanh with 10-way ILP, no memory op on the dependency chain.
// Block = 1 wave -> no barriers anywhere (per-wave DS ops are in-order).
__global__ __launch_bounds__(64, 1)
void rnn_row_kernel(const int* __restrict__ tok_ids,
                    const float* __restrict__ labels,
                    const float* __restrict__ emb,
                    const float* __restrict__ W,
                    const float* __restrict__ U,
                    const float* __restrict__ bvec,
                    const float* __restrict__ Wo,
                    const float* __restrict__ bo,
                    float* __restrict__ states_out,
                    float* __restrict__ probs_out,
                    float* __restrict__ ws)
{
    __shared__ __align__(16) float         s_st[64 * SROW];   // 85,248 B; preamble: raw labels
    __shared__ __align__(16) float         s_pr[64 * PROW];   // 25,856 B; preamble: raw tokens
    __shared__ __align__(16) unsigned char s_code[64 * CROW]; //  6,400 B  (sel<<2)|y per (row,t)
    __shared__ __align__(16) float         s_w[272];          //  1,088 B  weight staging

    const int l    = threadIdx.x;
    const int row0 = blockIdx.x * 64;

    // ---- preamble A: raw tokens -> s_pr (int4, software-pipelined groups) ----
    {
        const int4* tok4 = reinterpret_cast<const int4*>(tok_ids + (size_t)row0 * TT);
        int4* dst = reinterpret_cast<int4*>(s_pr);
        int4 buf[16];
#pragma unroll 1
        for (int g = 0; g < 2; ++g) {            // 2*16*64 = 2048 >= 1584 pieces
#pragma unroll
            for (int u = 0; u < 16; ++u) {
                const int q = l + 64 * (g * 16 + u);
                if (q < (TT * 64 / 4)) buf[u] = tok4[q];
            }
#pragma unroll
            for (int u = 0; u < 16; ++u) {
                const int q = l + 64 * (g * 16 + u);
                if (q < (TT * 64 / 4)) dst[q] = buf[u];
            }
        }
    }
    // ---- preamble B: raw labels -> s_st (float4 groups) ----
    {
        const float4* lab4 = reinterpret_cast<const float4*>(labels + (size_t)row0 * TT * LL);
        float4* dst = reinterpret_cast<float4*>(s_st);
        float4 buf[16];
#pragma unroll 1
        for (int g = 0; g < 5; ++g) {            // 5*16*64 = 5120 >= 4752 pieces
#pragma unroll
            for (int u = 0; u < 16; ++u) {
                const int q = l + 64 * (g * 16 + u);
                if (q < (TT * LL * 64 / 4)) buf[u] = lab4[q];
            }
#pragma unroll
            for (int u = 0; u < 16; ++u) {
                const int q = l + 64 * (g * 16 + u);
                if (q < (TT * LL * 64 / 4)) dst[q] = buf[u];
            }
        }
    }
    // ---- preamble C: weights -> LDS (strided so ALL 100 elems land) ----
#pragma unroll
    for (int q = 0; q < 2; ++q) {                 // covers 0..127 >= 100
        const int idx = l + 64 * q;
        if (idx < 100) { s_w[idx] = U[idx]; s_w[100 + idx] = W[idx]; }
    }
    if (l < 10)  { s_w[200 + l] = emb[10 + l];    // emb row 1
                   s_w[210 + l] = emb[20 + l];    // emb row 2
                   s_w[220 + l] = bvec[l]; }
    if (l < 30)  { s_w[230 + l] = Wo[l]; }
    if (l < 3)   { s_w[260 + l] = bo[l]; }

    // ---- preamble D: classify own row -> packed code bytes ----
    {
        const int* s_tok_i = reinterpret_cast<const int*>(s_pr);
#pragma unroll 4
        for (int t = 0; t < TT; ++t) {
            const int   tk  = s_tok_i[l * TT + t];
            const float la1 = s_st[(l * TT + t) * LL + 1];
            const float la2 = s_st[(l * TT + t) * LL + 2];
            const int   y   = (la1 > 0.5f) ? 1 : ((la2 > 0.5f) ? 2 : 0);
            s_code[l * CROW + t] = (unsigned char)((tk << 2) | y);
        }
    }

    // ---- weights: LDS -> VGPRs, PINNED so they stay register-resident ----
    float Uv[RR][RR];
#pragma unroll
    for (int i = 0; i < RR; ++i)
#pragma unroll
        for (int j = 0; j < RR; ++j) {
            Uv[i][j] = s_w[i * RR + j];
            KEEP(Uv[i][j]);
        }

    float c1[RR], c2[RR];
#pragma unroll
    for (int j = 0; j < RR; ++j) { c1[j] = s_w[220 + j]; c2[j] = s_w[220 + j]; }
#pragma unroll
    for (int i = 0; i < RR; ++i) {
        const float e1 = s_w[200 + i];
        const float e2 = s_w[210 + i];
#pragma unroll
        for (int j = 0; j < RR; ++j) {
            const float w = s_w[100 + i * RR + j];
            c1[j] = fmaf(e1, w, c1[j]);
            c2[j] = fmaf(e2, w, c2[j]);
        }
    }
#pragma unroll
    for (int j = 0; j < RR; ++j) { KEEP(c1[j]); KEEP(c2[j]); }

    float Woc[RR][LL];
#pragma unroll
    for (int j = 0; j < RR; ++j)
#pragma unroll
        for (int c = 0; c < LL; ++c) {
            Woc[j][c] = s_w[230 + j * LL + c];
            KEEP(Woc[j][c]);
        }
    float bo0 = s_w[260], bo1 = s_w[261], bo2 = s_w[262];
    KEEP(bo0); KEEP(bo1); KEEP(bo2);

    // ---- main sequential loop: register-only recurrence ----
    float h[RR];
#pragma unroll
    for (int j = 0; j < RR; ++j) h[j] = 0.0f;
    float loss_acc = 0.0f;
    int   corr = 0;

    int code = (int)s_code[l * CROW];            // prefetch t=0

#pragma unroll 1
    for (int k = 0; k < 3; ++k) {
#pragma unroll 1
        for (int tt = 0; tt < TILE; ++tt) {
            const int t   = k * TILE + tt;
            const int cur = code;
            const int tn  = (t + 1 < TT) ? t + 1 : t;
            code = (int)s_code[l * CROW + tn];   // prefetch next step

            const int  sel  = cur >> 2;
            const int  y    = cur & 3;
            const bool is1  = (sel == 1);
            const bool live = (sel != 0);

            float a[RR];
#pragma unroll
            for (int j = 0; j < RR; ++j) a[j] = is1 ? c1[j] : c2[j];
#pragma unroll
            for (int i = 0; i < RR; ++i) {
                const float hi = h[i];
#pragma unroll
                for (int j = 0; j < RR; ++j)
                    a[j] = fmaf(hi, Uv[i][j], a[j]);
            }
#pragma unroll
            for (int j = 0; j < RR; ++j) {
                const float hn = fast_tanh(a[j]);
                h[j] = live ? hn : h[j];          // Keras masking: carry h
            }

            // stage states (fire-and-forget, conflict-free stride)
            float* sp = &s_st[l * SROW + tt * RR];
#pragma unroll
            for (int j = 0; j < RR; ++j) sp[j] = h[j];

            // logits (10x3); softmax WITHOUT max-subtract (|logit| <~ 3)
            float l0 = bo0, l1 = bo1, l2 = bo2;
#pragma unroll
            for (int j = 0; j < RR; ++j) {
                l0 = fmaf(h[j], Woc[j][0], l0);
                l1 = fmaf(h[j], Woc[j][1], l1);
                l2 = fmaf(h[j], Woc[j][2], l2);
            }
            const float e0 = __expf(l0), e1 = __expf(l1), e2 = __expf(l2);
            const float S  = e0 + e1 + e2;
            const float rs = __builtin_amdgcn_rcpf(S);
            float* pp = &s_pr[l * PROW + tt * LL];
            pp[0] = e0 * rs; pp[1] = e1 * rs; pp[2] = e2 * rs;

            // loss: -log(clip(p_y)) == min(logS - l_y, -log(1e-7))
            const float ly   = (y == 0) ? l0 : ((y == 1) ? l1 : l2);
            const float term = fminf(__logf(S) - ly, 16.11809565f);
            loss_acc += term;

            // accuracy: argmax(probs) == argmax(logits) (monotonic, same ties)
            int ap = 0; float pm = l0;
            if (l1 > pm) { ap = 1; pm = l1; }
            if (l2 > pm) { ap = 2; }
            corr += (ap == y) ? 1 : 0;
        }

        // ---- flush states tile: LDS -> global, coalesced float2 ----
        {
            const size_t sb = (size_t)row0 * (TT * RR) + (size_t)k * TILE * RR;
#pragma unroll 4
            for (int i = 0; i < 165; ++i) {
                const int q  = l + 64 * i;
                const int r  = q / 165;
                const int m2 = q - r * 165;
                const float v0 = s_st[r * SROW + 2 * m2];
                const float v1 = s_st[r * SROW + 2 * m2 + 1];
                *reinterpret_cast<float2*>(
                    &states_out[sb + (size_t)r * (TT * RR) + 2 * m2]) = make_float2(v0, v1);
            }
        }
        // ---- flush probs tile: coalesced dwords ----
        {
            const size_t pb = (size_t)row0 * (TT * LL) + (size_t)k * TILE * LL;
#pragma unroll 4
            for (int i = 0; i < 99; ++i) {
                const int q  = l + 64 * i;
                const int r  = q / 99;
                const int m1 = q - r * 99;
                probs_out[pb + (size_t)r * (TT * LL) + m1] = s_pr[r * PROW + m1];
            }
        }
        // next tile reuses s_st/s_pr: same-wave DS ordering guarantees safety
    }

    // ---- wave reduction -> one partial per block (deterministic) ----
    float ls = loss_acc;
    float cs = (float)corr;
#pragma unroll
    for (int off = 32; off > 0; off >>= 1) {
        ls += __shfl_down(ls, off, 64);
        cs += __shfl_down(cs, off, 64);
    }
    if (l == 0) {
        ws[blockIdx.x]       = ls;
        ws[256 + blockIdx.x] = cs;
    }
}

__global__ __launch_bounds__(256)
void finalize_kernel(const float* __restrict__ ws, float* __restrict__ out_tail)
{
    __shared__ float sl[4], sc[4];
    const int t = threadIdx.x;
    float ls = ws[t];
    float cs = ws[256 + t];
#pragma unroll
    for (int off = 32; off > 0; off >>= 1) {
        ls += __shfl_down(ls, off, 64);
        cs += __shfl_down(cs, off, 64);
    }
    if ((t & 63) == 0) { sl[t >> 6] = ls; sc[t >> 6] = cs; }
    __syncthreads();
    if (t == 0) {
        const float L = sl[0] + sl[1] + sl[2] + sl[3];
        const float C = sc[0] + sc[1] + sc[2] + sc[3];
        const float inv = 1.0f / (float)((size_t)BB * TT);
        out_tail[0] = C * inv;   // accuracy
        out_tail[1] = L * inv;   // loss
    }
}

extern "C" void kernel_launch(void* const* d_in, const int* in_sizes, int n_in,
                              void* d_out, int out_size, void* d_ws, size_t ws_size,
                              hipStream_t stream)
{
    const int*   tok    = (const int*)  d_in[0];
    const float* labels = (const float*)d_in[1];
    // d_in[2] = mask (unused by reference math)
    const float* emb = (const float*)d_in[3];
    const float* W   = (const float*)d_in[4];
    const float* U   = (const float*)d_in[5];
    const float* bv  = (const float*)d_in[6];
    const float* Wo  = (const float*)d_in[7];
    const float* bo  = (const float*)d_in[8];

    float* out    = (float*)d_out;
    float* states = out;                                  // [B,T,10]
    float* probs  = out + (size_t)BB * TT * RR;           // [B,T,3]
    float* tail   = out + (size_t)BB * TT * (RR + LL);    // accuracy, loss
    float* ws     = (float*)d_ws;                         // 512 floats used

    rnn_row_kernel<<<BB / 64, 64, 0, stream>>>(tok, labels, emb, W, U, bv, Wo, bo,
                                               states, probs, ws);
    finalize_kernel<<<1, 256, 0, stream>>>(ws, tail);
}